// Round 7
// baseline (353.817 us; speedup 1.0000x reference)
//
#include <hip/hip_runtime.h>
#include <hip/hip_bf16.h>
#include <math.h>

#define EPSC 1e-5f

typedef __attribute__((ext_vector_type(8))) short bf16x8;
typedef __attribute__((ext_vector_type(4))) float f32x4;
typedef __attribute__((ext_vector_type(8))) unsigned short u16x8;

constexpr int Bn = 16, Cn = 96, Hn = 112, Wn = 112, HWn = Hn * Wn; // 12544
constexpr int NT = 64, TPI = HWn / NT;                             // 196 (fc1)
constexpr int TPM = HWn / 128;                                     // 98  (mega)

#define MFMA16(a, b, c) __builtin_amdgcn_mfma_f32_16x16x32_bf16((a), (b), (c), 0, 0, 0)

__device__ __forceinline__ ushort f2bf(float f) {
    __hip_bfloat16 h = __float2bfloat16(f);
    return __builtin_bit_cast(ushort, h);
}
__device__ __forceinline__ float bf2f(ushort u) {
    return __builtin_bit_cast(float, (unsigned)u << 16);
}
// tanh-form GELU: x * sigmoid(1.5957691*x + 0.0713548*x^3); |err| <= ~3e-4
__device__ __forceinline__ float gelu_f(float x) {
    float t = x * x;
    float z = x * fmaf(0.0713548162726f, t, 1.59576912161f);
    float e = __expf(-z);
    return __fdividef(x, 1.0f + e);
}
__device__ __forceinline__ uint pk2(float lo, float hi) {
    return (uint)f2bf(lo) | ((uint)f2bf(hi) << 16);
}

// ---------------- BN folding ----------------
// prm: A1[0:96] B1[96:192] Ag[192:384] Bg[384:576] A2[576:672] B2[672:768]
__global__ __launch_bounds__(256) void params_kernel(
    const float* __restrict__ b1, const float* __restrict__ g1, const float* __restrict__ be1,
    const float* __restrict__ m1, const float* __restrict__ v1,
    const float* __restrict__ bg, const float* __restrict__ gg, const float* __restrict__ beg,
    const float* __restrict__ mg, const float* __restrict__ vg,
    const float* __restrict__ b2, const float* __restrict__ g2, const float* __restrict__ be2,
    const float* __restrict__ m2, const float* __restrict__ v2,
    float* __restrict__ P)
{
    int t = threadIdx.x;
    if (t < 96) {
        float s = g1[t] * rsqrtf(v1[t] + EPSC);
        P[t]       = s;
        P[96 + t]  = (b1[t] - m1[t]) * s + be1[t];
        float s2 = g2[t] * rsqrtf(v2[t] + EPSC);
        P[576 + t] = s2;
        P[672 + t] = (b2[t] - m2[t]) * s2 + be2[t];
    }
    if (t < 192) {
        float s = gg[t] * rsqrtf(vg[t] + EPSC);
        P[192 + t] = s;
        P[384 + t] = (bg[t] - mg[t]) * s + beg[t];
    }
}

// ---------------- weight pack ----------------
// standard (w1, wg):  element (mt,kc,lane,e) = W[mt*16 + lane%16][kc*32 + (lane>>4)*8 + e]
// permuted (w2,wf1,wf2): k-col slot carries true channel
//   T = ((kc>>1)*4 + (kc&1)*2 + (e>>2))*16 + (lane>>4)*4 + (e&3)
// so the producer GEMM's D registers feed the consumer's B-frag with zero shuffles.
__global__ __launch_bounds__(256) void pack_kernel(
    const float* __restrict__ w1, const float* __restrict__ wg, const float* __restrict__ w2,
    const float* __restrict__ wf1, const float* __restrict__ wf2,
    ushort* __restrict__ dst)
{
    int idx = blockIdx.x * 256 + threadIdx.x;
    if (idx >= 138240) return;
    const float* src; int K, off; bool perm;
    if      (idx <   9216) { src = w1;  K =  96; off = 0;      perm = false; }
    else if (idx <  46080) { src = wg;  K = 192; off = 9216;   perm = false; }
    else if (idx <  64512) { src = w2;  K = 192; off = 46080;  perm = true;  }
    else if (idx < 101376) { src = wf1; K =  96; off = 64512;  perm = true;  }
    else                   { src = wf2; K = 384; off = 101376; perm = true;  }
    int r = idx - off;
    int e = r & 7, lane = (r >> 3) & 63, tile = r >> 9;
    int KC = K / 32;
    int kc = tile % KC, mt = tile / KC;
    int row = mt * 16 + (lane & 15);
    int col;
    if (!perm) col = kc * 32 + (lane >> 4) * 8 + e;
    else       col = ((kc >> 1) * 4 + (kc & 1) * 2 + (e >> 2)) * 16 + (lane >> 4) * 4 + (e & 3);
    dst[idx] = f2bf(src[(size_t)row * K + col]);
}

// ---------------- parity mins ----------------
__global__ __launch_bounds__(256) void mins_kernel(
    const ushort* __restrict__ h, float* __restrict__ rmin2, float* __restrict__ cmin2)
{
    __shared__ __align__(16) ushort sl[112 * 96];
    int bid = blockIdx.x;            // Bn * 2 * 112
    int b = bid / 224, rem = bid % 224, mode = rem / 112, line = rem % 112;
    int t = threadIdx.x;
    if (mode == 0) {
        const ushort* base = h + ((size_t)b * HWn + line * Wn) * Cn;
        for (int v = t; v < 1344; v += 256)
            *(u16x8*)&sl[v * 8] = *(const u16x8*)&base[v * 8];
    } else {
        for (int v = t; v < 1344; v += 256) {
            int i = v / 12, g = v % 12;
            *(u16x8*)&sl[(i * 12 + g) * 8] =
                *(const u16x8*)&h[((size_t)b * HWn + i * Wn + line) * Cn + g * 8];
        }
    }
    __syncthreads();
    if (t < 192) {
        int c = t % 96, p = t / 96;
        float m = 1e30f;
        #pragma unroll 8
        for (int n = 0; n < 56; ++n) m = fminf(m, bf2f(sl[(p + 2 * n) * 96 + c]));
        float* dst = (mode == 0) ? rmin2 : cmin2;
        dst[(((size_t)b * 112 + line) * 2 + p) * 96 + c] = m;
    }
}

// ---------------- fc1: h = BN(W1 x) -> bf16 [b][hw][96] ----------------
__global__ __launch_bounds__(256) void fc1_kernel(
    const float* __restrict__ X, const ushort* __restrict__ w1p,
    const float* __restrict__ prm, ushort* __restrict__ hbuf)
{
    __shared__ __align__(16) ushort Hs[64 * 104];
    int bid = blockIdx.x, b = bid / TPI, hw0 = (bid % TPI) * NT;
    int t = threadIdx.x, lane = t & 63, wave = t >> 6;
    int wm = wave >> 1, wn = wave & 1, q = lane >> 4, sl = lane & 15;

    bf16x8 bfr[3][2];
    #pragma unroll
    for (int kc = 0; kc < 3; ++kc)
        #pragma unroll
        for (int nc = 0; nc < 2; ++nc) {
            int s = hw0 + wn * 32 + nc * 16 + sl;
            union { bf16x8 v; ushort u[8]; } f;
            #pragma unroll
            for (int e = 0; e < 8; ++e) {
                int c = kc * 32 + q * 8 + e;
                f.u[e] = f2bf(X[((size_t)b * Cn + c) * HWn + s]);
            }
            bfr[kc][nc] = f.v;
        }
    f32x4 acc[3][2] = {};
    #pragma unroll
    for (int kc = 0; kc < 3; ++kc)
        #pragma unroll
        for (int m = 0; m < 3; ++m) {
            bf16x8 af = *(const bf16x8*)&w1p[(((wm * 3 + m) * 3 + kc) * 64 + lane) * 8];
            acc[m][0] = MFMA16(af, bfr[kc][0], acc[m][0]);
            acc[m][1] = MFMA16(af, bfr[kc][1], acc[m][1]);
        }
    #pragma unroll
    for (int m = 0; m < 3; ++m) {
        int o0 = (wm * 3 + m) * 16 + q * 4;
        f32x4 a4 = *(const f32x4*)&prm[o0];
        f32x4 s4 = *(const f32x4*)&prm[96 + o0];
        #pragma unroll
        for (int nc = 0; nc < 2; ++nc) {
            int srow = wn * 32 + nc * 16 + sl;
            ushort4 pk;
            pk.x = f2bf(acc[m][nc][0] * a4[0] + s4[0]);
            pk.y = f2bf(acc[m][nc][1] * a4[1] + s4[1]);
            pk.z = f2bf(acc[m][nc][2] * a4[2] + s4[2]);
            pk.w = f2bf(acc[m][nc][3] * a4[3] + s4[3]);
            *(ushort4*)&Hs[srow * 104 + o0] = pk;
        }
    }
    __syncthreads();
    for (int v = t; v < 768; v += 256) {
        int s = v / 12, g = v % 12;
        *(u16x8*)&hbuf[((size_t)b * HWn + hw0 + s) * Cn + g * 8] = *(const u16x8*)&Hs[s * 104 + g * 8];
    }
}

// ---------------- MEGA (N=32/wave): cat -> fcg+BN+GELU -> fc2+BN+res -> ffn1+GELU -> ffn2 -> out ----
// No LDS, no barriers. Each wave owns 32 spatial positions (2 B-frags), so every
// weight A-frag load feeds 2 MFMAs. D->B handoffs via permuted packs (validated r6).
__global__ __launch_bounds__(256, 2) void mega_kernel(
    const ushort* __restrict__ hbuf, const float* __restrict__ Xres,
    const ushort* __restrict__ wgp, const ushort* __restrict__ w2p,
    const ushort* __restrict__ wf1p, const ushort* __restrict__ wf2p,
    const float* __restrict__ prm, const float* __restrict__ bf1,
    const float* __restrict__ bf2,
    const float* __restrict__ cmin2, const float* __restrict__ rmin2,
    float* __restrict__ Out)
{
    int bid = blockIdx.x, b = bid / TPM, hw0 = (bid % TPM) * 128;
    int t = threadIdx.x, lane = t & 63, wv = t >> 6, q = lane >> 4, sl = lane & 15;
    union U8 { bf16x8 v; ushort u[8]; uint d[4]; };

    int ss[2];
    ss[0] = hw0 + wv * 32 + sl;
    ss[1] = ss[0] + 16;

    // ---- cat B-frags: kc 0..2 = h, kc 3..5 = xj ----
    U8 cb[6][2];
    #pragma unroll
    for (int n = 0; n < 2; ++n) {
        const int s = ss[n], i = s / Wn, j = s - i * Wn;
        const ushort* hrow = hbuf + ((size_t)b * HWn + s) * 96;
        const size_t cmb = (((size_t)b * 112 + j) * 2 + (i & 1)) * 96;
        const size_t rmb = (((size_t)b * 112 + i) * 2 + (j & 1)) * 96;
        #pragma unroll
        for (int kc = 0; kc < 3; ++kc) {
            cb[kc][n].v = *(const bf16x8*)&hrow[kc * 32 + q * 8];
            int c0 = kc * 32 + q * 8;
            f32x4 cma = *(const f32x4*)&cmin2[cmb + c0];
            f32x4 cmb2 = *(const f32x4*)&cmin2[cmb + c0 + 4];
            f32x4 rma = *(const f32x4*)&rmin2[rmb + c0];
            f32x4 rmb2 = *(const f32x4*)&rmin2[rmb + c0 + 4];
            U8 xx;
            #pragma unroll
            for (int e = 0; e < 4; ++e) {
                float hf = bf2f(cb[kc][n].u[e]);
                xx.u[e] = f2bf(fmaxf(hf - cma[e], hf - rma[e]));   // mins include self => >= 0
            }
            #pragma unroll
            for (int e = 0; e < 4; ++e) {
                float hf = bf2f(cb[kc][n].u[4 + e]);
                xx.u[4 + e] = f2bf(fmaxf(hf - cmb2[e], hf - rmb2[e]));
            }
            cb[3 + kc][n] = xx;
        }
    }

    // ---- fcg: M=192 (12 mt), K=192 (6 kc); each af feeds both n ----
    f32x4 ga[12][2] = {};
    #pragma unroll
    for (int kc = 0; kc < 6; ++kc)
        #pragma unroll
        for (int m = 0; m < 12; ++m) {
            bf16x8 af = *(const bf16x8*)&wgp[((m * 6 + kc) * 64 + lane) * 8];
            ga[m][0] = MFMA16(af, cb[kc][0].v, ga[m][0]);
            ga[m][1] = MFMA16(af, cb[kc][1].v, ga[m][1]);
        }
    uint gpk[12][2][2];
    #pragma unroll
    for (int m = 0; m < 12; ++m) {
        int t0 = m * 16 + q * 4;
        f32x4 a4 = *(const f32x4*)&prm[192 + t0];
        f32x4 s4 = *(const f32x4*)&prm[384 + t0];
        #pragma unroll
        for (int n = 0; n < 2; ++n) {
            gpk[m][n][0] = pk2(gelu_f(ga[m][n][0] * a4[0] + s4[0]), gelu_f(ga[m][n][1] * a4[1] + s4[1]));
            gpk[m][n][1] = pk2(gelu_f(ga[m][n][2] * a4[2] + s4[2]), gelu_f(ga[m][n][3] * a4[3] + s4[3]));
        }
    }

    // ---- fc2: M=96 (6 mt), K=192 permuted; + residual ----
    f32x4 r2[6][2] = {};
    #pragma unroll
    for (int kc = 0; kc < 6; ++kc) {
        int M = (kc >> 1) * 4 + (kc & 1) * 2;
        U8 gb[2];
        #pragma unroll
        for (int n = 0; n < 2; ++n) {
            gb[n].d[0] = gpk[M][n][0];     gb[n].d[1] = gpk[M][n][1];
            gb[n].d[2] = gpk[M + 1][n][0]; gb[n].d[3] = gpk[M + 1][n][1];
        }
        #pragma unroll
        for (int m = 0; m < 6; ++m) {
            bf16x8 af = *(const bf16x8*)&w2p[((m * 6 + kc) * 64 + lane) * 8];
            r2[m][0] = MFMA16(af, gb[0].v, r2[m][0]);
            r2[m][1] = MFMA16(af, gb[1].v, r2[m][1]);
        }
    }
    uint rpk[6][2][2];
    #pragma unroll
    for (int m = 0; m < 6; ++m) {
        int t0 = m * 16 + q * 4;
        f32x4 a4 = *(const f32x4*)&prm[576 + t0];
        f32x4 s4 = *(const f32x4*)&prm[672 + t0];
        #pragma unroll
        for (int n = 0; n < 2; ++n) {
            float rv[4];
            #pragma unroll
            for (int r = 0; r < 4; ++r)
                rv[r] = r2[m][n][r] * a4[r] + s4[r] + Xres[((size_t)b * 96 + t0 + r) * HWn + ss[n]];
            rpk[m][n][0] = pk2(rv[0], rv[1]);
            rpk[m][n][1] = pk2(rv[2], rv[3]);
        }
    }
    U8 rB[3][2];
    #pragma unroll
    for (int kc = 0; kc < 3; ++kc)
        #pragma unroll
        for (int n = 0; n < 2; ++n) {
            rB[kc][n].d[0] = rpk[kc * 2][n][0];     rB[kc][n].d[1] = rpk[kc * 2][n][1];
            rB[kc][n].d[2] = rpk[kc * 2 + 1][n][0]; rB[kc][n].d[3] = rpk[kc * 2 + 1][n][1];
        }

    // ---- ffn: 6 chunks of 64 mid channels, all in registers ----
    f32x4 oacc[6][2] = {};
    for (int c = 0; c < 6; ++c) {
        f32x4 a1[4][2] = {};
        #pragma unroll
        for (int kc = 0; kc < 3; ++kc)
            #pragma unroll
            for (int m = 0; m < 4; ++m) {
                bf16x8 af = *(const bf16x8*)&wf1p[(((c * 4 + m) * 3 + kc) * 64 + lane) * 8];
                a1[m][0] = MFMA16(af, rB[kc][0].v, a1[m][0]);
                a1[m][1] = MFMA16(af, rB[kc][1].v, a1[m][1]);
            }
        uint mpk[4][2][2];
        #pragma unroll
        for (int m = 0; m < 4; ++m) {
            f32x4 b4 = *(const f32x4*)&bf1[(c * 4 + m) * 16 + q * 4];
            #pragma unroll
            for (int n = 0; n < 2; ++n) {
                mpk[m][n][0] = pk2(gelu_f(a1[m][n][0] + b4[0]), gelu_f(a1[m][n][1] + b4[1]));
                mpk[m][n][1] = pk2(gelu_f(a1[m][n][2] + b4[2]), gelu_f(a1[m][n][3] + b4[3]));
            }
        }
        U8 mB0[2], mB1[2];
        #pragma unroll
        for (int n = 0; n < 2; ++n) {
            mB0[n].d[0] = mpk[0][n][0]; mB0[n].d[1] = mpk[0][n][1];
            mB0[n].d[2] = mpk[1][n][0]; mB0[n].d[3] = mpk[1][n][1];
            mB1[n].d[0] = mpk[2][n][0]; mB1[n].d[1] = mpk[2][n][1];
            mB1[n].d[2] = mpk[3][n][0]; mB1[n].d[3] = mpk[3][n][1];
        }
        #pragma unroll
        for (int m = 0; m < 6; ++m) {
            bf16x8 af0 = *(const bf16x8*)&wf2p[((m * 12 + c * 2) * 64 + lane) * 8];
            oacc[m][0] = MFMA16(af0, mB0[0].v, oacc[m][0]);
            oacc[m][1] = MFMA16(af0, mB0[1].v, oacc[m][1]);
            bf16x8 af1 = *(const bf16x8*)&wf2p[((m * 12 + c * 2 + 1) * 64 + lane) * 8];
            oacc[m][0] = MFMA16(af1, mB1[0].v, oacc[m][0]);
            oacc[m][1] = MFMA16(af1, mB1[1].v, oacc[m][1]);
        }
    }
    #pragma unroll
    for (int m = 0; m < 6; ++m) {
        int t0 = m * 16 + q * 4;
        f32x4 b4 = *(const f32x4*)&bf2[t0];
        #pragma unroll
        for (int n = 0; n < 2; ++n)
            #pragma unroll
            for (int r = 0; r < 4; ++r)
                Out[((size_t)b * 96 + t0 + r) * HWn + ss[n]] = oacc[m][n][r] + b4[r];
    }
}

extern "C" void kernel_launch(void* const* d_in, const int* in_sizes, int n_in,
                              void* d_out, int out_size, void* d_ws, size_t ws_size,
                              hipStream_t stream) {
    (void)in_sizes; (void)n_in; (void)out_size; (void)ws_size;
    const float* x   = (const float*)d_in[0];
    const float* w1  = (const float*)d_in[1];
    const float* b1  = (const float*)d_in[2];
    const float* g1  = (const float*)d_in[3];
    const float* be1 = (const float*)d_in[4];
    const float* m1  = (const float*)d_in[5];
    const float* v1  = (const float*)d_in[6];
    const float* wg  = (const float*)d_in[7];
    const float* bg  = (const float*)d_in[8];
    const float* gg  = (const float*)d_in[9];
    const float* beg = (const float*)d_in[10];
    const float* mg  = (const float*)d_in[11];
    const float* vg  = (const float*)d_in[12];
    const float* w2  = (const float*)d_in[13];
    const float* b2  = (const float*)d_in[14];
    const float* g2  = (const float*)d_in[15];
    const float* be2 = (const float*)d_in[16];
    const float* m2  = (const float*)d_in[17];
    const float* v2  = (const float*)d_in[18];
    const float* wf1 = (const float*)d_in[19];
    const float* bf1 = (const float*)d_in[20];
    const float* wf2 = (const float*)d_in[21];
    const float* bf2 = (const float*)d_in[22];
    float* out = (float*)d_out;

    char* base = (char*)d_ws;
    const size_t H_BYTES   = (size_t)Bn * HWn * Cn * 2;
    const size_t MIN_BYTES = (size_t)Bn * 112 * 2 * 96 * 4;
    ushort* hbuf  = (ushort*)base;
    float*  rmin2 = (float*)(base + H_BYTES);
    float*  cmin2 = (float*)(base + H_BYTES + MIN_BYTES);
    float*  prm   = (float*)(base + H_BYTES + 2 * MIN_BYTES);
    ushort* wpack = (ushort*)(base + H_BYTES + 2 * MIN_BYTES + 3072);
    ushort* w1p  = wpack;
    ushort* wgp  = wpack + 9216;
    ushort* w2p  = wpack + 46080;
    ushort* wf1p = wpack + 64512;
    ushort* wf2p = wpack + 101376;

    params_kernel<<<dim3(1), dim3(256), 0, stream>>>(
        b1, g1, be1, m1, v1, bg, gg, beg, mg, vg, b2, g2, be2, m2, v2, prm);
    pack_kernel<<<dim3(540), dim3(256), 0, stream>>>(w1, wg, w2, wf1, wf2, wpack);

    dim3 blk(256);
    fc1_kernel<<<dim3(Bn * TPI), blk, 0, stream>>>(x, w1p, prm, hbuf);
    mins_kernel<<<dim3(Bn * 2 * 112), blk, 0, stream>>>(hbuf, rmin2, cmin2);
    mega_kernel<<<dim3(Bn * TPM), blk, 0, stream>>>(hbuf, x, wgp, w2p, wf1p, wf2p,
                                                    prm, bf1, bf2, cmin2, rmin2, out);
}

// Round 8
// 269.967 us; speedup vs baseline: 1.3106x; 1.3106x over previous
//
#include <hip/hip_runtime.h>
#include <hip/hip_bf16.h>
#include <math.h>

#define EPSC 1e-5f

typedef __attribute__((ext_vector_type(8))) short bf16x8;
typedef __attribute__((ext_vector_type(4))) float f32x4;
typedef __attribute__((ext_vector_type(8))) unsigned short u16x8;

constexpr int Bn = 16, Cn = 96, Hn = 112, Wn = 112, HWn = Hn * Wn; // 12544
constexpr int NT = 64, TPI = HWn / NT;                             // 196 (fc1)
constexpr int TPM = HWn / 128;                                     // 98  (reg kernels)

#define MFMA16(a, b, c) __builtin_amdgcn_mfma_f32_16x16x32_bf16((a), (b), (c), 0, 0, 0)

__device__ __forceinline__ ushort f2bf(float f) {
    __hip_bfloat16 h = __float2bfloat16(f);
    return __builtin_bit_cast(ushort, h);
}
__device__ __forceinline__ float bf2f(ushort u) {
    return __builtin_bit_cast(float, (unsigned)u << 16);
}
// tanh-form GELU: x * sigmoid(1.5957691*x + 0.0713548*x^3); |err| <= ~3e-4
__device__ __forceinline__ float gelu_f(float x) {
    float t = x * x;
    float z = x * fmaf(0.0713548162726f, t, 1.59576912161f);
    float e = __expf(-z);
    return __fdividef(x, 1.0f + e);
}
__device__ __forceinline__ uint pk2(float lo, float hi) {
    return (uint)f2bf(lo) | ((uint)f2bf(hi) << 16);
}

// ---------------- BN folding ----------------
// prm: A1[0:96] B1[96:192] Ag[192:384] Bg[384:576] A2[576:672] B2[672:768]
__global__ __launch_bounds__(256) void params_kernel(
    const float* __restrict__ b1, const float* __restrict__ g1, const float* __restrict__ be1,
    const float* __restrict__ m1, const float* __restrict__ v1,
    const float* __restrict__ bg, const float* __restrict__ gg, const float* __restrict__ beg,
    const float* __restrict__ mg, const float* __restrict__ vg,
    const float* __restrict__ b2, const float* __restrict__ g2, const float* __restrict__ be2,
    const float* __restrict__ m2, const float* __restrict__ v2,
    float* __restrict__ P)
{
    int t = threadIdx.x;
    if (t < 96) {
        float s = g1[t] * rsqrtf(v1[t] + EPSC);
        P[t]       = s;
        P[96 + t]  = (b1[t] - m1[t]) * s + be1[t];
        float s2 = g2[t] * rsqrtf(v2[t] + EPSC);
        P[576 + t] = s2;
        P[672 + t] = (b2[t] - m2[t]) * s2 + be2[t];
    }
    if (t < 192) {
        float s = gg[t] * rsqrtf(vg[t] + EPSC);
        P[192 + t] = s;
        P[384 + t] = (bg[t] - mg[t]) * s + beg[t];
    }
}

// ---------------- weight pack ----------------
// standard (w1, wg, wf1): element (mt,kc,lane,e) = W[mt*16 + lane%16][kc*32 + (lane>>4)*8 + e]
// permuted (w2, wf2):     k-col slot carries the producer's D-register channel
//   T = ((kc>>1)*4 + (kc&1)*2 + (e>>2))*16 + (lane>>4)*4 + (e&3)
// so the producer GEMM's D registers feed the consumer's B-frag with zero shuffles.
__global__ __launch_bounds__(256) void pack_kernel(
    const float* __restrict__ w1, const float* __restrict__ wg, const float* __restrict__ w2,
    const float* __restrict__ wf1, const float* __restrict__ wf2,
    ushort* __restrict__ dst)
{
    int idx = blockIdx.x * 256 + threadIdx.x;
    if (idx >= 138240) return;
    const float* src; int K, off; bool perm;
    if      (idx <   9216) { src = w1;  K =  96; off = 0;      perm = false; }
    else if (idx <  46080) { src = wg;  K = 192; off = 9216;   perm = false; }
    else if (idx <  64512) { src = w2;  K = 192; off = 46080;  perm = true;  }
    else if (idx < 101376) { src = wf1; K =  96; off = 64512;  perm = false; }
    else                   { src = wf2; K = 384; off = 101376; perm = true;  }
    int r = idx - off;
    int e = r & 7, lane = (r >> 3) & 63, tile = r >> 9;
    int KC = K / 32;
    int kc = tile % KC, mt = tile / KC;
    int row = mt * 16 + (lane & 15);
    int col;
    if (!perm) col = kc * 32 + (lane >> 4) * 8 + e;
    else       col = ((kc >> 1) * 4 + (kc & 1) * 2 + (e >> 2)) * 16 + (lane >> 4) * 4 + (e & 3);
    dst[idx] = f2bf(src[(size_t)row * K + col]);
}

// ---------------- parity mins ----------------
__global__ __launch_bounds__(256) void mins_kernel(
    const ushort* __restrict__ h, float* __restrict__ rmin2, float* __restrict__ cmin2)
{
    __shared__ __align__(16) ushort sl[112 * 96];
    int bid = blockIdx.x;            // Bn * 2 * 112
    int b = bid / 224, rem = bid % 224, mode = rem / 112, line = rem % 112;
    int t = threadIdx.x;
    if (mode == 0) {
        const ushort* base = h + ((size_t)b * HWn + line * Wn) * Cn;
        for (int v = t; v < 1344; v += 256)
            *(u16x8*)&sl[v * 8] = *(const u16x8*)&base[v * 8];
    } else {
        for (int v = t; v < 1344; v += 256) {
            int i = v / 12, g = v % 12;
            *(u16x8*)&sl[(i * 12 + g) * 8] =
                *(const u16x8*)&h[((size_t)b * HWn + i * Wn + line) * Cn + g * 8];
        }
    }
    __syncthreads();
    if (t < 192) {
        int c = t % 96, p = t / 96;
        float m = 1e30f;
        #pragma unroll 8
        for (int n = 0; n < 56; ++n) m = fminf(m, bf2f(sl[(p + 2 * n) * 96 + c]));
        float* dst = (mode == 0) ? rmin2 : cmin2;
        dst[(((size_t)b * 112 + line) * 2 + p) * 96 + c] = m;
    }
}

// ---------------- fc1: h = BN(W1 x) -> bf16 [b][hw][96] ----------------
__global__ __launch_bounds__(256) void fc1_kernel(
    const float* __restrict__ X, const ushort* __restrict__ w1p,
    const float* __restrict__ prm, ushort* __restrict__ hbuf)
{
    __shared__ __align__(16) ushort Hs[64 * 104];
    int bid = blockIdx.x, b = bid / TPI, hw0 = (bid % TPI) * NT;
    int t = threadIdx.x, lane = t & 63, wave = t >> 6;
    int wm = wave >> 1, wn = wave & 1, q = lane >> 4, sl = lane & 15;

    bf16x8 bfr[3][2];
    #pragma unroll
    for (int kc = 0; kc < 3; ++kc)
        #pragma unroll
        for (int nc = 0; nc < 2; ++nc) {
            int s = hw0 + wn * 32 + nc * 16 + sl;
            union { bf16x8 v; ushort u[8]; } f;
            #pragma unroll
            for (int e = 0; e < 8; ++e) {
                int c = kc * 32 + q * 8 + e;
                f.u[e] = f2bf(X[((size_t)b * Cn + c) * HWn + s]);
            }
            bfr[kc][nc] = f.v;
        }
    f32x4 acc[3][2] = {};
    #pragma unroll
    for (int kc = 0; kc < 3; ++kc)
        #pragma unroll
        for (int m = 0; m < 3; ++m) {
            bf16x8 af = *(const bf16x8*)&w1p[(((wm * 3 + m) * 3 + kc) * 64 + lane) * 8];
            acc[m][0] = MFMA16(af, bfr[kc][0], acc[m][0]);
            acc[m][1] = MFMA16(af, bfr[kc][1], acc[m][1]);
        }
    #pragma unroll
    for (int m = 0; m < 3; ++m) {
        int o0 = (wm * 3 + m) * 16 + q * 4;
        f32x4 a4 = *(const f32x4*)&prm[o0];
        f32x4 s4 = *(const f32x4*)&prm[96 + o0];
        #pragma unroll
        for (int nc = 0; nc < 2; ++nc) {
            int srow = wn * 32 + nc * 16 + sl;
            ushort4 pk;
            pk.x = f2bf(acc[m][nc][0] * a4[0] + s4[0]);
            pk.y = f2bf(acc[m][nc][1] * a4[1] + s4[1]);
            pk.z = f2bf(acc[m][nc][2] * a4[2] + s4[2]);
            pk.w = f2bf(acc[m][nc][3] * a4[3] + s4[3]);
            *(ushort4*)&Hs[srow * 104 + o0] = pk;
        }
    }
    __syncthreads();
    for (int v = t; v < 768; v += 256) {
        int s = v / 12, g = v % 12;
        *(u16x8*)&hbuf[((size_t)b * HWn + hw0 + s) * Cn + g * 8] = *(const u16x8*)&Hs[s * 104 + g * 8];
    }
}

// ---------------- grapher-reg: cat -> [fcg-chunk -> fc2-acc] -> +res -> rbuf ----------------
// No LDS, no barriers. N=32/wave. fcg chunk mc = M-tiles {2mc,2mc+1}; its gelu'd
// output is exactly fc2's kc=mc B-frag via the permuted w2p pack (M(kc)=2kc).
__global__ __launch_bounds__(256, 2) void grapher_kernel(
    const ushort* __restrict__ hbuf, const float* __restrict__ Xres,
    const ushort* __restrict__ wgp, const ushort* __restrict__ w2p,
    const float* __restrict__ prm,
    const float* __restrict__ cmin2, const float* __restrict__ rmin2,
    ushort* __restrict__ rbuf)
{
    int bid = blockIdx.x, b = bid / TPM, hw0 = (bid % TPM) * 128;
    int t = threadIdx.x, lane = t & 63, wv = t >> 6, q = lane >> 4, sl = lane & 15;
    union U8 { bf16x8 v; ushort u[8]; uint d[4]; };
    int ss[2];
    ss[0] = hw0 + wv * 32 + sl;
    ss[1] = ss[0] + 16;

    // ---- cat B-frags in registers: kc 0..2 = h, kc 3..5 = xj ----
    U8 cb[6][2];
    #pragma unroll
    for (int n = 0; n < 2; ++n) {
        const int s = ss[n], i = s / Wn, j = s - i * Wn;
        const ushort* hrow = hbuf + ((size_t)b * HWn + s) * 96;
        const size_t cmb = (((size_t)b * 112 + j) * 2 + (i & 1)) * 96;
        const size_t rmb = (((size_t)b * 112 + i) * 2 + (j & 1)) * 96;
        #pragma unroll
        for (int kc = 0; kc < 3; ++kc) {
            cb[kc][n].v = *(const bf16x8*)&hrow[kc * 32 + q * 8];
            int c0 = kc * 32 + q * 8;
            f32x4 cma = *(const f32x4*)&cmin2[cmb + c0];
            f32x4 cmb2 = *(const f32x4*)&cmin2[cmb + c0 + 4];
            f32x4 rma = *(const f32x4*)&rmin2[rmb + c0];
            f32x4 rmb2 = *(const f32x4*)&rmin2[rmb + c0 + 4];
            U8 xx;
            #pragma unroll
            for (int e = 0; e < 4; ++e) {
                float hf = bf2f(cb[kc][n].u[e]);
                xx.u[e] = f2bf(fmaxf(hf - cma[e], hf - rma[e]));   // mins include self => >= 0
            }
            #pragma unroll
            for (int e = 0; e < 4; ++e) {
                float hf = bf2f(cb[kc][n].u[4 + e]);
                xx.u[4 + e] = f2bf(fmaxf(hf - cmb2[e], hf - rmb2[e]));
            }
            cb[3 + kc][n] = xx;
        }
    }

    // ---- fcg chunks (2 mt each) immediately consumed by fc2 ----
    f32x4 r2[6][2] = {};
    for (int mc = 0; mc < 6; ++mc) {
        f32x4 ga[2][2] = {};
        #pragma unroll
        for (int kc = 0; kc < 6; ++kc) {
            bf16x8 af0 = *(const bf16x8*)&wgp[(((2 * mc + 0) * 6 + kc) * 64 + lane) * 8];
            bf16x8 af1 = *(const bf16x8*)&wgp[(((2 * mc + 1) * 6 + kc) * 64 + lane) * 8];
            ga[0][0] = MFMA16(af0, cb[kc][0].v, ga[0][0]);
            ga[0][1] = MFMA16(af0, cb[kc][1].v, ga[0][1]);
            ga[1][0] = MFMA16(af1, cb[kc][0].v, ga[1][0]);
            ga[1][1] = MFMA16(af1, cb[kc][1].v, ga[1][1]);
        }
        uint gpk[2][2][2];
        #pragma unroll
        for (int mi = 0; mi < 2; ++mi) {
            int t0 = (2 * mc + mi) * 16 + q * 4;
            f32x4 a4 = *(const f32x4*)&prm[192 + t0];
            f32x4 s4 = *(const f32x4*)&prm[384 + t0];
            #pragma unroll
            for (int n = 0; n < 2; ++n) {
                gpk[mi][n][0] = pk2(gelu_f(ga[mi][n][0] * a4[0] + s4[0]),
                                    gelu_f(ga[mi][n][1] * a4[1] + s4[1]));
                gpk[mi][n][1] = pk2(gelu_f(ga[mi][n][2] * a4[2] + s4[2]),
                                    gelu_f(ga[mi][n][3] * a4[3] + s4[3]));
            }
        }
        U8 gb[2];
        #pragma unroll
        for (int n = 0; n < 2; ++n) {
            gb[n].d[0] = gpk[0][n][0]; gb[n].d[1] = gpk[0][n][1];
            gb[n].d[2] = gpk[1][n][0]; gb[n].d[3] = gpk[1][n][1];
        }
        #pragma unroll
        for (int m = 0; m < 6; ++m) {
            bf16x8 af = *(const bf16x8*)&w2p[((m * 6 + mc) * 64 + lane) * 8];
            r2[m][0] = MFMA16(af, gb[0].v, r2[m][0]);
            r2[m][1] = MFMA16(af, gb[1].v, r2[m][1]);
        }
    }

    // ---- epilogue: BN + residual -> bf16 rbuf (true channel order) ----
    #pragma unroll
    for (int m = 0; m < 6; ++m) {
        int t0 = m * 16 + q * 4;
        f32x4 a4 = *(const f32x4*)&prm[576 + t0];
        f32x4 s4 = *(const f32x4*)&prm[672 + t0];
        #pragma unroll
        for (int n = 0; n < 2; ++n) {
            float rv[4];
            #pragma unroll
            for (int r = 0; r < 4; ++r)
                rv[r] = r2[m][n][r] * a4[r] + s4[r] + Xres[((size_t)b * 96 + t0 + r) * HWn + ss[n]];
            ushort4 pk;
            pk.x = f2bf(rv[0]); pk.y = f2bf(rv[1]); pk.z = f2bf(rv[2]); pk.w = f2bf(rv[3]);
            *(ushort4*)&rbuf[((size_t)b * HWn + ss[n]) * 96 + t0] = pk;
        }
    }
}

// ---------------- ffn-reg: out = Wf2 gelu(Wf1 r + bf1) + bf2 ----------------
// No LDS, no barriers. rB loaded straight from global (true channels -> wf1p standard);
// mid stays in registers per chunk, consumed via permuted wf2p.
__global__ __launch_bounds__(256, 2) void ffn_kernel(
    const ushort* __restrict__ rbuf,
    const ushort* __restrict__ wf1p, const float* __restrict__ bf1,
    const ushort* __restrict__ wf2p, const float* __restrict__ bf2,
    float* __restrict__ Out)
{
    int bid = blockIdx.x, b = bid / TPM, hw0 = (bid % TPM) * 128;
    int t = threadIdx.x, lane = t & 63, wv = t >> 6, q = lane >> 4, sl = lane & 15;
    union U8 { bf16x8 v; ushort u[8]; uint d[4]; };
    int ss[2];
    ss[0] = hw0 + wv * 32 + sl;
    ss[1] = ss[0] + 16;

    bf16x8 rB[3][2];
    #pragma unroll
    for (int kc = 0; kc < 3; ++kc)
        #pragma unroll
        for (int n = 0; n < 2; ++n)
            rB[kc][n] = *(const bf16x8*)&rbuf[((size_t)b * HWn + ss[n]) * 96 + kc * 32 + q * 8];

    f32x4 oacc[6][2] = {};
    for (int c = 0; c < 6; ++c) {
        f32x4 a1[4][2] = {};
        #pragma unroll
        for (int kc = 0; kc < 3; ++kc)
            #pragma unroll
            for (int m = 0; m < 4; ++m) {
                bf16x8 af = *(const bf16x8*)&wf1p[(((c * 4 + m) * 3 + kc) * 64 + lane) * 8];
                a1[m][0] = MFMA16(af, rB[kc][0], a1[m][0]);
                a1[m][1] = MFMA16(af, rB[kc][1], a1[m][1]);
            }
        uint mpk[4][2][2];
        #pragma unroll
        for (int m = 0; m < 4; ++m) {
            f32x4 b4 = *(const f32x4*)&bf1[(c * 4 + m) * 16 + q * 4];
            #pragma unroll
            for (int n = 0; n < 2; ++n) {
                mpk[m][n][0] = pk2(gelu_f(a1[m][n][0] + b4[0]), gelu_f(a1[m][n][1] + b4[1]));
                mpk[m][n][1] = pk2(gelu_f(a1[m][n][2] + b4[2]), gelu_f(a1[m][n][3] + b4[3]));
            }
        }
        U8 mB0[2], mB1[2];
        #pragma unroll
        for (int n = 0; n < 2; ++n) {
            mB0[n].d[0] = mpk[0][n][0]; mB0[n].d[1] = mpk[0][n][1];
            mB0[n].d[2] = mpk[1][n][0]; mB0[n].d[3] = mpk[1][n][1];
            mB1[n].d[0] = mpk[2][n][0]; mB1[n].d[1] = mpk[2][n][1];
            mB1[n].d[2] = mpk[3][n][0]; mB1[n].d[3] = mpk[3][n][1];
        }
        #pragma unroll
        for (int m = 0; m < 6; ++m) {
            bf16x8 af0 = *(const bf16x8*)&wf2p[((m * 12 + c * 2) * 64 + lane) * 8];
            oacc[m][0] = MFMA16(af0, mB0[0].v, oacc[m][0]);
            oacc[m][1] = MFMA16(af0, mB0[1].v, oacc[m][1]);
            bf16x8 af1 = *(const bf16x8*)&wf2p[((m * 12 + c * 2 + 1) * 64 + lane) * 8];
            oacc[m][0] = MFMA16(af1, mB1[0].v, oacc[m][0]);
            oacc[m][1] = MFMA16(af1, mB1[1].v, oacc[m][1]);
        }
    }
    #pragma unroll
    for (int m = 0; m < 6; ++m) {
        int t0 = m * 16 + q * 4;
        f32x4 b4 = *(const f32x4*)&bf2[t0];
        #pragma unroll
        for (int n = 0; n < 2; ++n)
            #pragma unroll
            for (int r = 0; r < 4; ++r)
                Out[((size_t)b * 96 + t0 + r) * HWn + ss[n]] = oacc[m][n][r] + b4[r];
    }
}

extern "C" void kernel_launch(void* const* d_in, const int* in_sizes, int n_in,
                              void* d_out, int out_size, void* d_ws, size_t ws_size,
                              hipStream_t stream) {
    (void)in_sizes; (void)n_in; (void)out_size; (void)ws_size;
    const float* x   = (const float*)d_in[0];
    const float* w1  = (const float*)d_in[1];
    const float* b1  = (const float*)d_in[2];
    const float* g1  = (const float*)d_in[3];
    const float* be1 = (const float*)d_in[4];
    const float* m1  = (const float*)d_in[5];
    const float* v1  = (const float*)d_in[6];
    const float* wg  = (const float*)d_in[7];
    const float* bg  = (const float*)d_in[8];
    const float* gg  = (const float*)d_in[9];
    const float* beg = (const float*)d_in[10];
    const float* mg  = (const float*)d_in[11];
    const float* vg  = (const float*)d_in[12];
    const float* w2  = (const float*)d_in[13];
    const float* b2  = (const float*)d_in[14];
    const float* g2  = (const float*)d_in[15];
    const float* be2 = (const float*)d_in[16];
    const float* m2  = (const float*)d_in[17];
    const float* v2  = (const float*)d_in[18];
    const float* wf1 = (const float*)d_in[19];
    const float* bf1 = (const float*)d_in[20];
    const float* wf2 = (const float*)d_in[21];
    const float* bf2 = (const float*)d_in[22];
    float* out = (float*)d_out;

    char* base = (char*)d_ws;
    const size_t H_BYTES   = (size_t)Bn * HWn * Cn * 2;
    const size_t MIN_BYTES = (size_t)Bn * 112 * 2 * 96 * 4;
    ushort* hbuf  = (ushort*)base;                         // h, overwritten by r
    float*  rmin2 = (float*)(base + H_BYTES);
    float*  cmin2 = (float*)(base + H_BYTES + MIN_BYTES);
    float*  prm   = (float*)(base + H_BYTES + 2 * MIN_BYTES);
    ushort* wpack = (ushort*)(base + H_BYTES + 2 * MIN_BYTES + 3072);
    ushort* w1p  = wpack;
    ushort* wgp  = wpack + 9216;
    ushort* w2p  = wpack + 46080;
    ushort* wf1p = wpack + 64512;
    ushort* wf2p = wpack + 101376;

    params_kernel<<<dim3(1), dim3(256), 0, stream>>>(
        b1, g1, be1, m1, v1, bg, gg, beg, mg, vg, b2, g2, be2, m2, v2, prm);
    pack_kernel<<<dim3(540), dim3(256), 0, stream>>>(w1, wg, w2, wf1, wf2, wpack);

    dim3 blk(256);
    fc1_kernel<<<dim3(Bn * TPI), blk, 0, stream>>>(x, w1p, prm, hbuf);
    mins_kernel<<<dim3(Bn * 2 * 112), blk, 0, stream>>>(hbuf, rmin2, cmin2);
    grapher_kernel<<<dim3(Bn * TPM), blk, 0, stream>>>(hbuf, x, wgp, w2p,
                                                       prm, cmin2, rmin2, hbuf);
    ffn_kernel<<<dim3(Bn * TPM), blk, 0, stream>>>(hbuf, wf1p, bf1, wf2p, bf2, out);
}